// Round 2
// baseline (174.628 us; speedup 1.0000x reference)
//
#include <hip/hip_runtime.h>

#define MA 64
#define F 128
#define NF 16
#define HID 512
#define LDUB 144    // ub row stride BYTES (128 fp8 + 16 pad)
#define LDWB 144    // wL row stride bytes (64 bf16 + 8 pad elems)
#define LDT1B 1040  // t1 row stride bytes (512 bf16 + 8 pad elems)
// double-buffer base offsets (bytes)
#define UB0 0
#define UB1 9216
#define WL0 18432
#define WL1 27648

typedef float  float4v __attribute__((ext_vector_type(4)));
typedef short  short8  __attribute__((ext_vector_type(8)));
typedef int    int8v   __attribute__((ext_vector_type(8)));

// pack two fp32 -> (bf16(y)<<16)|bf16(x), round-half-up via +0x8000 then v_perm
static __device__ __forceinline__ unsigned int pack2bf(float x, float y) {
    unsigned int a = __float_as_uint(x) + 0x8000u;
    unsigned int b = __float_as_uint(y) + 0x8000u;
    return __builtin_amdgcn_perm(b, a, 0x07060302u);
}
static __device__ __forceinline__ unsigned short f2bf1(float x) {
    return (unsigned short)((__float_as_uint(x) + 0x8000u) >> 16);
}
// pack 4 fp32 -> 4 fp8 e4m3 (RNE, saturating) in one dword
static __device__ __forceinline__ unsigned int pk4fp8(float a, float b, float c, float d) {
    int p = __builtin_amdgcn_cvt_pk_fp8_f32(a, b, 0, false);
    p = __builtin_amdgcn_cvt_pk_fp8_f32(c, d, p, true);
    return (unsigned int)p;
}

// lgkm-only barrier: LDS producer/consumer sync WITHOUT draining vmcnt, so
// global prefetches (afr / aw2) stay in flight across the rendezvous.
#define LGKM_BAR() do {                                        \
    asm volatile("s_waitcnt lgkmcnt(0)" ::: "memory");         \
    __builtin_amdgcn_s_barrier();                              \
    asm volatile("" ::: "memory");                             \
} while (0)

// ---- Pack W1 as fp8 MX A-frags (16x16x128) of W1^T; W2 as bf16 A-frags
// (16x16x32) of W2^T. Direct gather. (unchanged)
__global__ void pack_frags(const float* __restrict__ W1, const float* __restrict__ W2,
                           unsigned char* __restrict__ w1p, unsigned short* __restrict__ w2p) {
    int gid  = blockIdx.x * 4 + (threadIdx.x >> 6);
    int lane = threadIdx.x & 63;
    int arow = lane & 15;
    int kq   = lane >> 4;
    if (gid < 544) {                           // W1: kt (17 over K=2176, 128 each) x jt (32)
        int kt = gid >> 5, jt = gid & 31;
        const float* base = W1 + (size_t)(kt * 128 + kq * 32) * HID + jt * 16 + arow;
        unsigned int o[8];
        #pragma unroll
        for (int p = 0; p < 8; p++)
            o[p] = pk4fp8(base[(p * 4 + 0) * HID], base[(p * 4 + 1) * HID],
                          base[(p * 4 + 2) * HID], base[(p * 4 + 3) * HID]);
        unsigned char* dst = w1p + ((size_t)gid * 64 + lane) * 32;
        *(uint4*)dst        = (uint4){o[0], o[1], o[2], o[3]};
        *(uint4*)(dst + 16) = (uint4){o[4], o[5], o[6], o[7]};
    } else if (gid < 544 + 128) {              // W2: kt (16 over J=512) x mt (8 over 128)
        int g2 = gid - 544;
        int kt = g2 >> 3, mt = g2 & 7;
        const float* base = W2 + (size_t)(kt * 32 + kq * 8) * F + mt * 16 + arow;
        short8 o;
        #pragma unroll
        for (int j = 0; j < 8; j++) o[j] = (short)f2bf1(base[j * F]);
        *(short8*)(w2p + ((size_t)g2 * 64 + lane) * 8) = o;
    }
}

// ---- Main fused kernel: ONE molecule per block, 512 threads = 8 waves ----
// launch_bounds(512,4): 4 waves/EU -> 2 BLOCKS/CU co-resident (reg total must
// fit 128/wave: acc 64 AGPR + <=64 VGPR). A-frags are STREAMED 2-deep (16
// regs) instead of the old 4-frag buffer (32 regs); W2 frags streamed 2-deep
// in GEMM2 (was a 64-reg bulk preload). LDS 68 KB x 2 = 136 <= 160 KB/CU.
__launch_bounds__(512, 4)
__global__ void node_conv_mfma(const int* __restrict__ z, const float* __restrict__ rr,
        const float* __restrict__ h, const float* __restrict__ dist,
        const float* __restrict__ wid, const float* __restrict__ b1,
        const float* __restrict__ b2,
        const unsigned char* __restrict__ w1p, const unsigned short* __restrict__ w2p,
        float* __restrict__ out) {
    const int n = blockIdx.x;                  // molecule index
    const int tid = threadIdx.x;
    const int lane = tid & 63;
    const int wave = tid >> 6;
    const int arow = lane & 15;
    const int quad = lane >> 4;
    const int kgrp = quad * 8;

    __shared__ __attribute__((aligned(16))) unsigned char lds[66560];
    __shared__ float r_lds[MA][5];             // xyz + mask, stride-5

    const int N = gridDim.x;
    const float* hg = h + (size_t)n * MA * F;

    // ---- z / r passthrough + r/mask staging ----
    if (tid < MA) {
        int zi = z[n * MA + tid];
        out[(size_t)n * MA + tid] = (float)zi;
        r_lds[tid][0] = rr[(n * MA + tid) * 3 + 0];
        r_lds[tid][1] = rr[(n * MA + tid) * 3 + 1];
        r_lds[tid][2] = rr[(n * MA + tid) * 3 + 2];
        r_lds[tid][3] = (zi > -1) ? 1.0f : 0.0f;
    }
    if (tid < MA * 3)
        out[(size_t)N * MA + (size_t)n * MA * 3 + tid] = rr[(size_t)n * MA * 3 + tid];

    // ---- stage h -> ub0 (row-major fp8) ----
    for (int i = tid; i < MA * F / 4; i += 512) {
        float4 v = ((const float4*)hg)[i];
        int a = i >> 5, c4 = (i & 31) * 4;
        *(unsigned int*)&lds[UB0 + a * LDUB + c4] = pk4fp8(v.x, v.y, v.z, v.w);
    }
    // ---- hT A-fragments held in registers (bf16): lane holds h[b][c], c = wave*16+arow ----
    short8 ah[2];
    {
        int c = wave * 16 + arow;
        #pragma unroll
        for (int ks2 = 0; ks2 < 2; ks2++)
            #pragma unroll
            for (int j = 0; j < 8; j++)
                ah[ks2][j] = (short)f2bf1(hg[(size_t)(ks2 * 32 + kgrp + j) * F + c]);
    }
    __syncthreads();                           // r_lds + ub0 staged h visible (full drain, once)

    // ---- per-thread pairwise distances, mask folded in ----
    const int wa = tid >> 3;
    const int wb0 = (tid & 7) * 8;
    float dpre[8];
    {
        float ax = r_lds[wa][0], ay = r_lds[wa][1], az = r_lds[wa][2];
        float am = r_lds[wa][3];
        #pragma unroll
        for (int j = 0; j < 8; j++) {
            float dx = ax - r_lds[wb0 + j][0];
            float dy = ay - r_lds[wb0 + j][1];
            float dz = az - r_lds[wb0 + j][2];
            float d = sqrtf(dx * dx + dy * dy + dz * dz + 1e-12f);
            float mm = am * r_lds[wb0 + j][3];
            dpre[j] = d + (1.0f - mm) * 1e4f;
        }
    }

    // ---- prime: w filter 0 -> wL0 (bf16), A-frag pair (seg 0, mt 0/1) ----
    {
        float mu = dist[0];
        float isg = 1.0f / wid[0];
        float e[8];
        #pragma unroll
        for (int j = 0; j < 8; j++) {
            float t = dpre[j] - mu;
            e[j] = 5.0f * __expf(-t * t * isg);
        }
        uint4 wp = { pack2bf(e[0], e[1]), pack2bf(e[2], e[3]),
                     pack2bf(e[4], e[5]), pack2bf(e[6], e[7]) };
        *(uint4*)&lds[WL0 + wa * LDWB + wb0 * 2] = wp;
    }
    int8v afrA, afrB;                          // streamed MX A-frag pair (16 regs)
    {
        const unsigned char* p0 = w1p + ((size_t)((wave * 4) * 64 + lane)) * 32;
        afrA = *(const int8v*)p0;              // (seg 0, mt 0)
        afrB = *(const int8v*)(p0 + 2048);     // (seg 0, mt 1)
    }
    LGKM_BAR();                                // w0 + ub0 visible; afr loads ride through

    const float4v zf = {0.f, 0.f, 0.f, 0.f};
    float4v acc[4][4];                         // [j-tile][a-tile] = 64 AGPRs
    #pragma unroll
    for (int i = 0; i < 4; i++)
        #pragma unroll
        for (int jv = 0; jv < 4; jv++) acc[i][jv] = zf;

    // ---- main loop: 17 K-segments of 128, ONE lgkm barrier per iteration.
    // GEMM1 runs in two mt-pair halves; the afrA/afrB pair is overwritten by
    // the (mt 2,3) loads mid-iteration (WAR: safe, MFMA reads at issue) and by
    // the next segment's (mt 0,1) during the u-GEMM. Exposed L2 latency is
    // hidden by the 4-waves/SIMD TLP this reg-diet buys.
    for (int f = 0; f <= NF; f++) {
        const int sel = f & 1;
        const int ubR = sel ? UB1 : UB0;
        const int ubW = sel ? UB0 : UB1;
        const int wlR = sel ? WL1 : WL0;
        const int wlW = sel ? WL0 : WL1;
        const unsigned char* pseg = w1p + ((size_t)((f * 32 + wave * 4) * 64 + lane)) * 32;

        // GEMM1 half 1: mt 0,1 (E8M0 scale 127 = 1.0)
        #pragma unroll
        for (int at = 0; at < 4; at++) {
            int8v bfr = *(const int8v*)&lds[ubR + (at * 16 + arow) * LDUB + quad * 32];
            acc[0][at] = __builtin_amdgcn_mfma_scale_f32_16x16x128_f8f6f4(
                afrA, bfr, acc[0][at], 0, 0, 0, 127, 0, 127);
            acc[1][at] = __builtin_amdgcn_mfma_scale_f32_16x16x128_f8f6f4(
                afrB, bfr, acc[1][at], 0, 0, 0, 127, 0, 127);
        }
        // stream in mt 2,3 of this segment
        afrA = *(const int8v*)(pseg + 2 * 2048);
        afrB = *(const int8v*)(pseg + 3 * 2048);
        // GEMM1 half 2: mt 2,3
        #pragma unroll
        for (int at = 0; at < 4; at++) {
            int8v bfr = *(const int8v*)&lds[ubR + (at * 16 + arow) * LDUB + quad * 32];
            acc[2][at] = __builtin_amdgcn_mfma_scale_f32_16x16x128_f8f6f4(
                afrA, bfr, acc[2][at], 0, 0, 0, 127, 0, 127);
            acc[3][at] = __builtin_amdgcn_mfma_scale_f32_16x16x128_f8f6f4(
                afrB, bfr, acc[3][at], 0, 0, 0, 127, 0, 127);
        }

        if (f < NF) {
            // prefetch next segment's (mt 0,1); rides across the barrier
            const unsigned char* pN = w1p + ((size_t)(((f + 1) * 32 + wave * 4) * 64 + lane)) * 32;
            afrA = *(const int8v*)pN;
            afrB = *(const int8v*)(pN + 2048);

            // u-GEMM: u_f^T = hT @ w_f (bf16, w symmetric), per at-pair to cap
            // register pressure (ud live = 8 regs, was 16)
            #pragma unroll
            for (int atp = 0; atp < 2; atp++) {
                float4v ud0 = zf, ud1 = zf;
                #pragma unroll
                for (int ks2 = 0; ks2 < 2; ks2++) {
                    short8 bw0 = *(const short8*)&lds[wlR + ((atp * 2 + 0) * 16 + arow) * LDWB + (ks2 * 32 + kgrp) * 2];
                    ud0 = __builtin_amdgcn_mfma_f32_16x16x32_bf16(ah[ks2], bw0, ud0, 0, 0, 0);
                    short8 bw1 = *(const short8*)&lds[wlR + ((atp * 2 + 1) * 16 + arow) * LDWB + (ks2 * 32 + kgrp) * 2];
                    ud1 = __builtin_amdgcn_mfma_f32_16x16x32_bf16(ah[ks2], bw1, ud1, 0, 0, 0);
                }
                unsigned int u0 = pk4fp8(ud0[0], ud0[1], ud0[2], ud0[3]);
                unsigned int u1 = pk4fp8(ud1[0], ud1[1], ud1[2], ud1[3]);
                *(unsigned int*)&lds[ubW + ((atp * 2 + 0) * 16 + arow) * LDUB + wave * 16 + quad * 4] = u0;
                *(unsigned int*)&lds[ubW + ((atp * 2 + 1) * 16 + arow) * LDUB + wave * 16 + quad * 4] = u1;
            }

            if (f <= NF - 2) {                 // exp w_{f+1} -> write buffer
                float mu = dist[f + 1];
                float isg = 1.0f / wid[f + 1];
                float e[8];
                #pragma unroll
                for (int j = 0; j < 8; j++) {
                    float t = dpre[j] - mu;
                    e[j] = 5.0f * __expf(-t * t * isg);
                }
                uint4 wp = { pack2bf(e[0], e[1]), pack2bf(e[2], e[3]),
                             pack2bf(e[4], e[5]), pack2bf(e[6], e[7]) };
                *(uint4*)&lds[wlW + wa * LDWB + wb0 * 2] = wp;
            }
        }
        LGKM_BAR();                            // u_f + w_{f+1} visible / final: ub reads drained
    }

    // ---- GEMM2 (bf16): out = h + 0.1*mask*(silu(t1) @ W2 + b2) ----
    // Full t1 (64 x 512) staged once (overlays ub/wL). W2 A-frags streamed
    // 2-deep (16 regs) from L2-resident w2p instead of a 64-reg preload.
    float4 b1v[4];
    #pragma unroll
    for (int mt = 0; mt < 4; mt++)
        b1v[mt] = *(const float4*)&b1[wave * 64 + mt * 16 + quad * 4];

    #pragma unroll
    for (int mt = 0; mt < 4; mt++) {
        #pragma unroll
        for (int at = 0; at < 4; at++) {
            float xs[4];
            #pragma unroll
            for (int r = 0; r < 4; r++) {
                float x = acc[mt][at][r] + ((const float*)&b1v[mt])[r];
                xs[r] = x / (1.0f + __expf(-x));
            }
            uint2 pv = { pack2bf(xs[0], xs[1]), pack2bf(xs[2], xs[3]) };
            *(uint2*)&lds[(at * 16 + arow) * LDT1B + (wave * 64 + mt * 16 + quad * 4) * 2] = pv;
        }
    }
    LGKM_BAR();                                // full t1 visible; aw2 stream rides through

    float4v g2[4];
    #pragma unroll
    for (int n2 = 0; n2 < 4; n2++) g2[n2] = zf;

    short8 awA = *(const short8*)(w2p + ((size_t)(wave) * 64 + lane) * 8);  // ks=0
    #pragma unroll
    for (int ks2 = 0; ks2 < 8; ks2++) {
        const int k1 = 2 * ks2 + 1;
        short8 awB = *(const short8*)(w2p + ((size_t)(k1 * 8 + wave) * 64 + lane) * 8);
        #pragma unroll
        for (int n2 = 0; n2 < 4; n2++) {
            short8 bt = *(const short8*)&lds[(n2 * 16 + arow) * LDT1B + ((2 * ks2) * 32 + kgrp) * 2];
            g2[n2] = __builtin_amdgcn_mfma_f32_16x16x32_bf16(awA, bt, g2[n2], 0, 0, 0);
        }
        const int k2 = (ks2 < 7) ? 2 * ks2 + 2 : 0;   // harmless re-read of frag 0 on last iter
        awA = *(const short8*)(w2p + ((size_t)(k2 * 8 + wave) * 64 + lane) * 8);
        #pragma unroll
        for (int n2 = 0; n2 < 4; n2++) {
            short8 bt = *(const short8*)&lds[(n2 * 16 + arow) * LDT1B + ((2 * ks2 + 1) * 32 + kgrp) * 2];
            g2[n2] = __builtin_amdgcn_mfma_f32_16x16x32_bf16(awB, bt, g2[n2], 0, 0, 0);
        }
    }

    // D[m=c][n=a]: a = n2*16+arow, c = wave*16+quad*4 + r
    float* outh = out + (size_t)N * MA * 4 + (size_t)n * MA * F;
    const int c0 = wave * 16 + quad * 4;
    float4 b2v = *(const float4*)&b2[c0];
    #pragma unroll
    for (int n2 = 0; n2 < 4; n2++) {
        int a = n2 * 16 + arow;
        float m = r_lds[a][3] * 0.1f;
        float4 hv = *(const float4*)&hg[a * F + c0];
        float4 res;
        res.x = hv.x + (g2[n2][0] + b2v.x) * m;
        res.y = hv.y + (g2[n2][1] + b2v.y) * m;
        res.z = hv.z + (g2[n2][2] + b2v.z) * m;
        res.w = hv.w + (g2[n2][3] + b2v.w) * m;
        *(float4*)&outh[(size_t)a * F + c0] = res;
    }
}

extern "C" void kernel_launch(void* const* d_in, const int* in_sizes, int n_in,
                              void* d_out, int out_size, void* d_ws, size_t ws_size,
                              hipStream_t stream) {
    const int*   z    = (const int*)d_in[0];
    const float* rr   = (const float*)d_in[1];
    const float* h    = (const float*)d_in[2];
    const float* dist = (const float*)d_in[3];
    const float* wid  = (const float*)d_in[4];
    const float* W1   = (const float*)d_in[5];
    const float* b1   = (const float*)d_in[6];
    const float* W2   = (const float*)d_in[7];
    const float* b2   = (const float*)d_in[8];
    float* out = (float*)d_out;

    int Nmol = in_sizes[0] / MA;                           // 512 molecules

    unsigned char*  w1p = (unsigned char*)d_ws;            // 544*64*32 = 1,114,112 B
    unsigned short* w2p = (unsigned short*)(w1p + (size_t)544 * 64 * 32);  // 128 KB bf16

    pack_frags<<<168, 256, 0, stream>>>(W1, W2, w1p, w2p);
    node_conv_mfma<<<Nmol, 512, 0, stream>>>(z, rr, h, dist, wid, b1, b2, w1p, w2p, out);
}

// Round 3
// 144.565 us; speedup vs baseline: 1.2080x; 1.2080x over previous
//
#include <hip/hip_runtime.h>

#define MA 64
#define F 128
#define NF 16
#define HID 512
#define LDUB 144    // ub row stride BYTES (128 fp8 + 16 pad)
#define LDWB 144    // wL row stride bytes (64 bf16 + 8 pad elems)
#define LDT1B 1040  // t1 row stride bytes (512 bf16 + 8 pad elems)
// double-buffer base offsets (bytes)
#define UB0 0
#define UB1 9216
#define WL0 18432
#define WL1 27648

typedef float  float4v __attribute__((ext_vector_type(4)));
typedef short  short8  __attribute__((ext_vector_type(8)));
typedef int    int8v   __attribute__((ext_vector_type(8)));

// pack two fp32 -> (bf16(y)<<16)|bf16(x), round-half-up via +0x8000 then v_perm
static __device__ __forceinline__ unsigned int pack2bf(float x, float y) {
    unsigned int a = __float_as_uint(x) + 0x8000u;
    unsigned int b = __float_as_uint(y) + 0x8000u;
    return __builtin_amdgcn_perm(b, a, 0x07060302u);
}
static __device__ __forceinline__ unsigned short f2bf1(float x) {
    return (unsigned short)((__float_as_uint(x) + 0x8000u) >> 16);
}
// pack 4 fp32 -> 4 fp8 e4m3 (RNE, saturating) in one dword
static __device__ __forceinline__ unsigned int pk4fp8(float a, float b, float c, float d) {
    int p = __builtin_amdgcn_cvt_pk_fp8_f32(a, b, 0, false);
    p = __builtin_amdgcn_cvt_pk_fp8_f32(c, d, p, true);
    return (unsigned int)p;
}

// lgkm-only barrier: LDS producer/consumer sync WITHOUT draining vmcnt, so
// global prefetches (afr / aw2) stay in flight across the rendezvous.
#define LGKM_BAR() do {                                        \
    asm volatile("s_waitcnt lgkmcnt(0)" ::: "memory");         \
    __builtin_amdgcn_s_barrier();                              \
    asm volatile("" ::: "memory");                             \
} while (0)

// ---- Pack W1 as fp8 MX A-frags (16x16x128) of W1^T; W2 as bf16 A-frags
// (16x16x32) of W2^T. Direct gather. (unchanged)
__global__ void pack_frags(const float* __restrict__ W1, const float* __restrict__ W2,
                           unsigned char* __restrict__ w1p, unsigned short* __restrict__ w2p) {
    int gid  = blockIdx.x * 4 + (threadIdx.x >> 6);
    int lane = threadIdx.x & 63;
    int arow = lane & 15;
    int kq   = lane >> 4;
    if (gid < 544) {                           // W1: kt (17 over K=2176, 128 each) x jt (32)
        int kt = gid >> 5, jt = gid & 31;
        const float* base = W1 + (size_t)(kt * 128 + kq * 32) * HID + jt * 16 + arow;
        unsigned int o[8];
        #pragma unroll
        for (int p = 0; p < 8; p++)
            o[p] = pk4fp8(base[(p * 4 + 0) * HID], base[(p * 4 + 1) * HID],
                          base[(p * 4 + 2) * HID], base[(p * 4 + 3) * HID]);
        unsigned char* dst = w1p + ((size_t)gid * 64 + lane) * 32;
        *(uint4*)dst        = (uint4){o[0], o[1], o[2], o[3]};
        *(uint4*)(dst + 16) = (uint4){o[4], o[5], o[6], o[7]};
    } else if (gid < 544 + 128) {              // W2: kt (16 over J=512) x mt (8 over 128)
        int g2 = gid - 544;
        int kt = g2 >> 3, mt = g2 & 7;
        const float* base = W2 + (size_t)(kt * 32 + kq * 8) * F + mt * 16 + arow;
        short8 o;
        #pragma unroll
        for (int j = 0; j < 8; j++) o[j] = (short)f2bf1(base[j * F]);
        *(short8*)(w2p + ((size_t)g2 * 64 + lane) * 8) = o;
    }
}

// ---- Main fused kernel: ONE molecule per block, 1024 threads = 16 waves ----
// 16 waves / 4 SIMDs = 4 waves/SIMD from a SINGLE block (no 2-block reg
// squeeze -> no spill). Per-wave j-tile halves: acc[2][4] = 32 AGPR; live set
// ~105 regs < 128 budget. LDS unchanged (67.8 KB, 1 block/CU).
// Partition: GEMM1 jt = wave*2+mt; u-GEMM c-slice = (wave>>1)*16, at-pair =
// wave&1; GEMM2 c-tile = wave>>1, a-pair = wave&1; exp fill 4 pairs/thread.
__launch_bounds__(1024, 4)
__global__ void node_conv_mfma(const int* __restrict__ z, const float* __restrict__ rr,
        const float* __restrict__ h, const float* __restrict__ dist,
        const float* __restrict__ wid, const float* __restrict__ b1,
        const float* __restrict__ b2,
        const unsigned char* __restrict__ w1p, const unsigned short* __restrict__ w2p,
        float* __restrict__ out) {
    const int n = blockIdx.x;                  // molecule index
    const int tid = threadIdx.x;
    const int lane = tid & 63;
    const int wave = tid >> 6;                 // 0..15
    const int arow = lane & 15;
    const int quad = lane >> 4;
    const int kgrp = quad * 8;
    const int whi = wave >> 1;                 // 0..7: c-slice (u-GEMM / GEMM2)
    const int wlo = wave & 1;                  // a-pair selector

    __shared__ __attribute__((aligned(16))) unsigned char lds[66560];
    __shared__ float r_lds[MA][5];             // xyz + mask, stride-5

    const int N = gridDim.x;
    const float* hg = h + (size_t)n * MA * F;

    // ---- z / r passthrough + r/mask staging ----
    if (tid < MA) {
        int zi = z[n * MA + tid];
        out[(size_t)n * MA + tid] = (float)zi;
        r_lds[tid][0] = rr[(n * MA + tid) * 3 + 0];
        r_lds[tid][1] = rr[(n * MA + tid) * 3 + 1];
        r_lds[tid][2] = rr[(n * MA + tid) * 3 + 2];
        r_lds[tid][3] = (zi > -1) ? 1.0f : 0.0f;
    }
    if (tid < MA * 3)
        out[(size_t)N * MA + (size_t)n * MA * 3 + tid] = rr[(size_t)n * MA * 3 + tid];

    // ---- stage h -> ub0 (row-major fp8) ----
    for (int i = tid; i < MA * F / 4; i += 1024) {
        float4 v = ((const float4*)hg)[i];
        int a = i >> 5, c4 = (i & 31) * 4;
        *(unsigned int*)&lds[UB0 + a * LDUB + c4] = pk4fp8(v.x, v.y, v.z, v.w);
    }
    // ---- hT A-fragments in registers (bf16): lane holds h[b][c], c = whi*16+arow
    // (wave pairs sharing whi load duplicates; L1/L2 absorbs) ----
    short8 ah[2];
    {
        int c = whi * 16 + arow;
        #pragma unroll
        for (int ks2 = 0; ks2 < 2; ks2++)
            #pragma unroll
            for (int j = 0; j < 8; j++)
                ah[ks2][j] = (short)f2bf1(hg[(size_t)(ks2 * 32 + kgrp + j) * F + c]);
    }
    __syncthreads();                           // r_lds + ub0 staged h visible (full drain, once)

    // ---- per-thread pairwise distances (4 pairs/thread), mask folded in ----
    const int wa = tid >> 4;                   // 0..63
    const int wb0 = (tid & 15) * 4;            // 0,4,..,60
    float dpre[4];
    {
        float ax = r_lds[wa][0], ay = r_lds[wa][1], az = r_lds[wa][2];
        float am = r_lds[wa][3];
        #pragma unroll
        for (int j = 0; j < 4; j++) {
            float dx = ax - r_lds[wb0 + j][0];
            float dy = ay - r_lds[wb0 + j][1];
            float dz = az - r_lds[wb0 + j][2];
            float d = sqrtf(dx * dx + dy * dy + dz * dz + 1e-12f);
            float mm = am * r_lds[wb0 + j][3];
            dpre[j] = d + (1.0f - mm) * 1e4f;
        }
    }

    // ---- prime: w filter 0 -> wL0 (bf16), A-frag pair (seg 0) ----
    {
        float mu = dist[0];
        float isg = 1.0f / wid[0];
        float e[4];
        #pragma unroll
        for (int j = 0; j < 4; j++) {
            float t = dpre[j] - mu;
            e[j] = 5.0f * __expf(-t * t * isg);
        }
        uint2 wp = { pack2bf(e[0], e[1]), pack2bf(e[2], e[3]) };
        *(uint2*)&lds[WL0 + wa * LDWB + wb0 * 2] = wp;
    }
    int8v afr[2];                              // this wave's 2 MX A-frags (16 regs)
    {
        const unsigned char* p0 = w1p + ((size_t)((wave * 2) * 64 + lane)) * 32;
        afr[0] = *(const int8v*)p0;            // (seg 0, jt = wave*2)
        afr[1] = *(const int8v*)(p0 + 2048);   // (seg 0, jt = wave*2+1)
    }
    LGKM_BAR();                                // w0 + ub0 visible; afr loads ride through

    const float4v zf = {0.f, 0.f, 0.f, 0.f};
    float4v acc[2][4];                         // [mt][at] = 32 AGPRs
    #pragma unroll
    for (int i = 0; i < 2; i++)
        #pragma unroll
        for (int jv = 0; jv < 4; jv++) acc[i][jv] = zf;

    // ---- main loop: 17 K-segments of 128, ONE lgkm barrier per iteration ----
    for (int f = 0; f <= NF; f++) {
        const int sel = f & 1;
        const int ubR = sel ? UB1 : UB0;
        const int ubW = sel ? UB0 : UB1;
        const int wlR = sel ? WL1 : WL0;
        const int wlW = sel ? WL0 : WL1;

        // GEMM1 seg f: 8 scale-MFMA (E8M0 scale 127 = 1.0)
        #pragma unroll
        for (int at = 0; at < 4; at++) {
            int8v bfr = *(const int8v*)&lds[ubR + (at * 16 + arow) * LDUB + quad * 32];
            acc[0][at] = __builtin_amdgcn_mfma_scale_f32_16x16x128_f8f6f4(
                afr[0], bfr, acc[0][at], 0, 0, 0, 127, 0, 127);
            acc[1][at] = __builtin_amdgcn_mfma_scale_f32_16x16x128_f8f6f4(
                afr[1], bfr, acc[1][at], 0, 0, 0, 127, 0, 127);
        }

        if (f < NF) {
            // prefetch next segment's frag pair (WAR on afr: MFMA reads done);
            // loads ride across the lgkm-only barrier
            const unsigned char* pN = w1p + ((size_t)(((f + 1) * 32 + wave * 2) * 64 + lane)) * 32;
            afr[0] = *(const int8v*)pN;
            afr[1] = *(const int8v*)(pN + 2048);

            // u-GEMM: u_f^T = hT @ w_f (bf16); this wave: c-slice whi, at-pair wlo
            float4v ud0 = zf, ud1 = zf;
            #pragma unroll
            for (int ks2 = 0; ks2 < 2; ks2++) {
                short8 bw0 = *(const short8*)&lds[wlR + ((wlo * 2 + 0) * 16 + arow) * LDWB + (ks2 * 32 + kgrp) * 2];
                ud0 = __builtin_amdgcn_mfma_f32_16x16x32_bf16(ah[ks2], bw0, ud0, 0, 0, 0);
                short8 bw1 = *(const short8*)&lds[wlR + ((wlo * 2 + 1) * 16 + arow) * LDWB + (ks2 * 32 + kgrp) * 2];
                ud1 = __builtin_amdgcn_mfma_f32_16x16x32_bf16(ah[ks2], bw1, ud1, 0, 0, 0);
            }
            unsigned int u0 = pk4fp8(ud0[0], ud0[1], ud0[2], ud0[3]);
            unsigned int u1 = pk4fp8(ud1[0], ud1[1], ud1[2], ud1[3]);
            *(unsigned int*)&lds[ubW + ((wlo * 2 + 0) * 16 + arow) * LDUB + whi * 16 + quad * 4] = u0;
            *(unsigned int*)&lds[ubW + ((wlo * 2 + 1) * 16 + arow) * LDUB + whi * 16 + quad * 4] = u1;

            if (f <= NF - 2) {                 // exp w_{f+1} -> write buffer
                float mu = dist[f + 1];
                float isg = 1.0f / wid[f + 1];
                float e[4];
                #pragma unroll
                for (int j = 0; j < 4; j++) {
                    float t = dpre[j] - mu;
                    e[j] = 5.0f * __expf(-t * t * isg);
                }
                uint2 wp = { pack2bf(e[0], e[1]), pack2bf(e[2], e[3]) };
                *(uint2*)&lds[wlW + wa * LDWB + wb0 * 2] = wp;
            }
        }
        LGKM_BAR();                            // u_f + w_{f+1} visible / final: ub reads drained
    }

    // ---- GEMM2 (bf16): out = h + 0.1*mask*(silu(t1) @ W2 + b2) ----
    // Full t1 (64 x 512) staged once (overlays ub/wL). W2 A-frags streamed
    // 2-deep from L2-resident w2p.
    float4 b1v[2];
    #pragma unroll
    for (int mt = 0; mt < 2; mt++)
        b1v[mt] = *(const float4*)&b1[wave * 32 + mt * 16 + quad * 4];

    #pragma unroll
    for (int mt = 0; mt < 2; mt++) {
        #pragma unroll
        for (int at = 0; at < 4; at++) {
            float xs[4];
            #pragma unroll
            for (int r = 0; r < 4; r++) {
                float x = acc[mt][at][r] + ((const float*)&b1v[mt])[r];
                xs[r] = x / (1.0f + __expf(-x));
            }
            uint2 pv = { pack2bf(xs[0], xs[1]), pack2bf(xs[2], xs[3]) };
            *(uint2*)&lds[(at * 16 + arow) * LDT1B + (wave * 32 + mt * 16 + quad * 4) * 2] = pv;
        }
    }
    LGKM_BAR();                                // full t1 visible; aw2 stream rides through

    float4v g2[2] = { zf, zf };                // this wave: c-tile whi, a-pair wlo

    short8 awA = *(const short8*)(w2p + ((size_t)(whi) * 64 + lane) * 8);   // ks=0
    #pragma unroll
    for (int ks2 = 0; ks2 < 8; ks2++) {
        const int k1 = 2 * ks2 + 1;
        short8 awB = *(const short8*)(w2p + ((size_t)(k1 * 8 + whi) * 64 + lane) * 8);
        #pragma unroll
        for (int j = 0; j < 2; j++) {
            short8 bt = *(const short8*)&lds[((wlo * 2 + j) * 16 + arow) * LDT1B + ((2 * ks2) * 32 + kgrp) * 2];
            g2[j] = __builtin_amdgcn_mfma_f32_16x16x32_bf16(awA, bt, g2[j], 0, 0, 0);
        }
        const int k2 = (ks2 < 7) ? 2 * ks2 + 2 : 0;   // harmless re-read on last iter
        awA = *(const short8*)(w2p + ((size_t)(k2 * 8 + whi) * 64 + lane) * 8);
        #pragma unroll
        for (int j = 0; j < 2; j++) {
            short8 bt = *(const short8*)&lds[((wlo * 2 + j) * 16 + arow) * LDT1B + ((2 * ks2 + 1) * 32 + kgrp) * 2];
            g2[j] = __builtin_amdgcn_mfma_f32_16x16x32_bf16(awB, bt, g2[j], 0, 0, 0);
        }
    }

    // D[m=c][n=a]: a = (wlo*2+j)*16+arow, c = whi*16 + quad*4 + r
    float* outh = out + (size_t)N * MA * 4 + (size_t)n * MA * F;
    const int c0 = whi * 16 + quad * 4;
    float4 b2v = *(const float4*)&b2[c0];
    #pragma unroll
    for (int j = 0; j < 2; j++) {
        int a = (wlo * 2 + j) * 16 + arow;
        float m = r_lds[a][3] * 0.1f;
        float4 hv = *(const float4*)&hg[a * F + c0];
        float4 res;
        res.x = hv.x + (g2[j][0] + b2v.x) * m;
        res.y = hv.y + (g2[j][1] + b2v.y) * m;
        res.z = hv.z + (g2[j][2] + b2v.z) * m;
        res.w = hv.w + (g2[j][3] + b2v.w) * m;
        *(float4*)&outh[(size_t)a * F + c0] = res;
    }
}

extern "C" void kernel_launch(void* const* d_in, const int* in_sizes, int n_in,
                              void* d_out, int out_size, void* d_ws, size_t ws_size,
                              hipStream_t stream) {
    const int*   z    = (const int*)d_in[0];
    const float* rr   = (const float*)d_in[1];
    const float* h    = (const float*)d_in[2];
    const float* dist = (const float*)d_in[3];
    const float* wid  = (const float*)d_in[4];
    const float* W1   = (const float*)d_in[5];
    const float* b1   = (const float*)d_in[6];
    const float* W2   = (const float*)d_in[7];
    const float* b2   = (const float*)d_in[8];
    float* out = (float*)d_out;

    int Nmol = in_sizes[0] / MA;                           // 512 molecules

    unsigned char*  w1p = (unsigned char*)d_ws;            // 544*64*32 = 1,114,112 B
    unsigned short* w2p = (unsigned short*)(w1p + (size_t)544 * 64 * 32);  // 128 KB bf16

    pack_frags<<<168, 256, 0, stream>>>(W1, W2, w1p, w2p);
    node_conv_mfma<<<Nmol, 1024, 0, stream>>>(z, rr, h, dist, wid, b1, b2, w1p, w2p, out);
}